// Round 1
// baseline (1789.280 us; speedup 1.0000x reference)
//
#include <hip/hip_runtime.h>
#include <math.h>

#define NT 17
#define CH 48
#define KCAP 300
#define NITER 30
#define TAUINV 20.0f

typedef unsigned long long u64;

// ---- meta layout (ints at ws start, zeroed each launch) ----
// [0..31]   typeCount
// [32..63]  typeOff
// [64..95]  scatterCnt
// [96]      doneFlag
// [97]      barrier counter
// [98]      NC (number of real chunks)
// [128..]   chunkMeta: 4 ints per chunk (type, startSortedRow, nRows, pad)
// [768..]   chunkStart[17] (first chunk id of type)
// [800..]   chunkCnt[17]

__device__ inline u64 packf2(float m, float s) {
  return ((u64)__float_as_uint(s) << 32) | (u64)__float_as_uint(m);
}

__device__ inline float selu_f(float x) {
  const float scale = 1.0507009873554804934193349852946f;
  const float alpha = 1.6732632423543772848170429916717f;
  return x > 0.f ? scale * x : scale * alpha * expm1f(x);
}

__global__ void k_hist(const int* __restrict__ jt, int n, int* meta) {
  int i = blockIdx.x * 256 + threadIdx.x;
  if (i < n) atomicAdd(&meta[jt[i]], 1);
  __syncthreads();
  if (threadIdx.x == 0) {
    __threadfence();
    int d = atomicAdd(&meta[96], 1);
    if (d == (int)gridDim.x - 1) {
      int off = 0, nc = 0;
      for (int t = 0; t < NT; t++) {
        int c = __hip_atomic_load(&meta[t], __ATOMIC_RELAXED, __HIP_MEMORY_SCOPE_AGENT);
        meta[32 + t] = off;
        meta[768 + t] = nc;
        int ncs = (c + CH - 1) / CH;
        meta[800 + t] = ncs;
        int pos = off;
        for (int q = 0; q < ncs; q++) {
          int len = c - q * CH; if (len > CH) len = CH;
          meta[128 + 4 * nc + 0] = t;
          meta[128 + 4 * nc + 1] = pos;
          meta[128 + 4 * nc + 2] = len;
          nc++; pos += len;
        }
        off += c;
      }
      meta[98] = nc;
      __threadfence();
    }
  }
}

__global__ void k_scatter(const int* __restrict__ jt, int n, int* meta,
                          int* __restrict__ perm, int* __restrict__ tys) {
  int i = blockIdx.x * 256 + threadIdx.x;
  if (i < n) {
    int t = jt[i];
    int pos = meta[32 + t] + atomicAdd(&meta[64 + t], 1);
    perm[pos] = i;
    tys[pos] = t;
  }
}

// h = selu(emb @ W1 + b1)   (n x D) @ (D x H)
__global__ __launch_bounds__(256) void k_hgemm(const float* __restrict__ A,
    const float* __restrict__ B, const float* __restrict__ bias,
    float* __restrict__ C, int n, int D, int H) {
  __shared__ __align__(16) float As[16][68];
  __shared__ __align__(16) float Bs[16][68];
  int tid = threadIdx.x;
  int i0 = blockIdx.x * 64, j0 = blockIdx.y * 64;
  int tx = tid & 15, ty = tid >> 4;
  int aI = tid & 63, aK = (tid >> 6) << 2;
  int bJ = (tid & 15) << 2, bK = tid >> 4;
  float acc[4][4] = {};
  for (int k0 = 0; k0 < D; k0 += 16) {
    float4 av = *(const float4*)(A + (size_t)(i0 + aI) * D + k0 + aK);
    float4 bv = *(const float4*)(B + (size_t)(k0 + bK) * H + j0 + bJ);
    __syncthreads();
    As[aK + 0][aI] = av.x; As[aK + 1][aI] = av.y; As[aK + 2][aI] = av.z; As[aK + 3][aI] = av.w;
    *(float4*)(&Bs[bK][bJ]) = bv;
    __syncthreads();
#pragma unroll
    for (int kk = 0; kk < 16; kk++) {
      float4 a4 = *(float4*)(&As[kk][ty << 2]);
      float4 b4 = *(float4*)(&Bs[kk][tx << 2]);
      float aa[4] = {a4.x, a4.y, a4.z, a4.w};
      float bb[4] = {b4.x, b4.y, b4.z, b4.w};
#pragma unroll
      for (int p = 0; p < 4; p++)
#pragma unroll
        for (int q = 0; q < 4; q++)
          acc[p][q] = fmaf(aa[p], bb[q], acc[p][q]);
    }
  }
#pragma unroll
  for (int p = 0; p < 4; p++) {
    int i = i0 + (ty << 2) + p;
    float o[4];
#pragma unroll
    for (int q = 0; q < 4; q++) {
      int j = j0 + (tx << 2) + q;
      o[q] = selu_f(acc[p][q] + bias[j]);
    }
    *(float4*)(C + (size_t)i * H + j0 + (tx << 2)) = make_float4(o[0], o[1], o[2], o[3]);
  }
}

// row norms of h (n rows) and prototypes (k rows)
__global__ __launch_bounds__(256) void k_norms(const float* __restrict__ h,
    const float* __restrict__ P, float* __restrict__ hsq, float* __restrict__ psq,
    int n, int H, int k) {
  int wv = threadIdx.x >> 6, lane = threadIdx.x & 63;
  int idx = blockIdx.x * 4 + wv;
  const float* src; float* dst;
  if (idx < n) { src = h + (size_t)idx * H; dst = hsq + idx; }
  else if (idx < n + k) { int j = idx - n; src = P + (size_t)j * H; dst = psq + j; }
  else return;
  float s = 0.f;
  for (int d = lane * 4; d < H; d += 256) {
    float4 v = *(const float4*)(src + d);
    s += v.x * v.x + v.y * v.y + v.z * v.z + v.w * v.w;
  }
#pragma unroll
  for (int o = 32; o; o >>= 1) s += __shfl_xor(s, o);
  if (lane == 0) *dst = s;
}

// Msort[r][j] = -max(0, hsq+psq-2*dot)/tau  with rows gathered via perm (type-sorted)
__global__ __launch_bounds__(256) void k_msort(const float* __restrict__ h,
    const float* __restrict__ P, const float* __restrict__ hsq,
    const float* __restrict__ psq, const int* __restrict__ perm,
    float* __restrict__ Ms, int n, int H, int k) {
  __shared__ __align__(16) float As[16][68];
  __shared__ __align__(16) float Bs[16][68];
  __shared__ int gIdx[64];
  int tid = threadIdx.x;
  int i0 = blockIdx.x * 64, j0 = blockIdx.y * 64;
  if (tid < 64) gIdx[tid] = perm[i0 + tid];
  __syncthreads();
  int tx = tid & 15, ty = tid >> 4;
  int aI = tid & 63, aK = (tid >> 6) << 2;
  int gA = gIdx[aI];
  bool bok = (j0 + aI) < k;
  const float* bRow = P + (size_t)(j0 + (bok ? aI : 0)) * H;
  float acc[4][4] = {};
  for (int k0 = 0; k0 < H; k0 += 16) {
    float4 av = *(const float4*)(h + (size_t)gA * H + k0 + aK);
    float4 bv = *(const float4*)(bRow + k0 + aK);
    __syncthreads();
    As[aK + 0][aI] = av.x; As[aK + 1][aI] = av.y; As[aK + 2][aI] = av.z; As[aK + 3][aI] = av.w;
    Bs[aK + 0][aI] = bv.x; Bs[aK + 1][aI] = bv.y; Bs[aK + 2][aI] = bv.z; Bs[aK + 3][aI] = bv.w;
    __syncthreads();
#pragma unroll
    for (int kk = 0; kk < 16; kk++) {
      float4 a4 = *(float4*)(&As[kk][ty << 2]);
      float4 b4 = *(float4*)(&Bs[kk][tx << 2]);
      float aa[4] = {a4.x, a4.y, a4.z, a4.w};
      float bb[4] = {b4.x, b4.y, b4.z, b4.w};
#pragma unroll
      for (int p = 0; p < 4; p++)
#pragma unroll
        for (int q = 0; q < 4; q++)
          acc[p][q] = fmaf(aa[p], bb[q], acc[p][q]);
    }
  }
#pragma unroll
  for (int p = 0; p < 4; p++) {
    int rr = (ty << 2) + p;
    int r = i0 + rr;
    float hq = hsq[gIdx[rr]];
#pragma unroll
    for (int q = 0; q < 4; q++) {
      int j = j0 + (tx << 2) + q;
      if (j < k) {
        float d2 = hq + psq[j] - 2.f * acc[p][q];
        d2 = fmaxf(d2, 0.f);
        Ms[(size_t)r * k + j] = -d2 * TAUINV;
      }
    }
  }
}

// Persistent Sinkhorn: one type-pure 48-row chunk per block, M in LDS (col-major, stride 49).
__global__ __launch_bounds__(256) void k_sink(const float* __restrict__ Ms,
    const int* __restrict__ meta, u64* __restrict__ pcol, u64* __restrict__ plu,
    float* __restrict__ luF, float* __restrict__ VF,
    int k, int NCmax, float tm_last) {
  __shared__ float Mc[KCAP * 49];
  __shared__ float V[KCAP];
  __shared__ float lu[CH];
  __shared__ float rpM[4][CH];
  __shared__ float rpS[4][CH];
  __shared__ float lvlast_sh;
  int tid = threadIdx.x, lane = tid & 63, wv = tid >> 6;
  int c = blockIdx.x;
  int NC = meta[98];
  bool active = (c < NC);
  int t = 0, s0 = 0, cR = 0, cS = 0, cN = 0;
  if (active) {
    t  = meta[128 + 4 * c + 0];
    s0 = meta[128 + 4 * c + 1];
    cR = meta[128 + 4 * c + 2];
    cS = meta[768 + t];
    cN = meta[800 + t];
  }
  unsigned* bar = (unsigned*)(meta + 97);
  if (active) {
    const float* src = Ms + (size_t)s0 * k;
    for (int r = 0; r < cR; r++)
      for (int j = tid; j < k; j += 256)
        Mc[j * 49 + r] = src[(size_t)r * k + j];
  }
  for (int j = tid; j < k; j += 256) V[j] = 0.f;
  if (tid == 0) lvlast_sh = 0.f;
  __syncthreads();

  for (int m = 0; m < NITER; m++) {
    u64* pc = pcol + (size_t)(m & 1) * NCmax * k;
    u64* pl = plu + (size_t)(m & 1) * NCmax;
    if (active) {
      // row pass: lanes = rows, waves split the j range; online lse
      int jw0 = (k * wv) >> 2, jw1 = (k * (wv + 1)) >> 2;
      int rr = (lane < cR) ? lane : 0;
      float om = -3.0e38f, os = 0.f;
      for (int j = jw0; j < jw1; j++) {
        float x = Mc[j * 49 + rr] + V[j];
        float nm = fmaxf(om, x);
        os = os * expf(om - nm) + expf(x - nm);
        om = nm;
      }
      if (lane < cR) { rpM[wv][lane] = om; rpS[wv][lane] = os; }
    }
    __syncthreads();
    if (active && wv == 0 && lane < cR) {
      float mm = lvlast_sh, ss = 1.f;  // extra column term exp(lvlast)
#pragma unroll
      for (int q = 0; q < 4; q++) {
        float mq = rpM[q][lane], sq = rpS[q][lane];
        float nm = fmaxf(mm, mq);
        ss = ss * expf(mm - nm) + sq * expf(mq - nm);
        mm = nm;
      }
      lu[lane] = -(mm + logf(ss));
    }
    __syncthreads();
    if (active) {
      // column partials: threads = columns, serial over rows; online lse
      for (int j = tid; j < k; j += 256) {
        float om = -3.0e38f, os = 0.f;
        for (int r = 0; r < cR; r++) {
          float x = Mc[j * 49 + r] + lu[r];
          float nm = fmaxf(om, x);
          os = os * expf(om - nm) + expf(x - nm);
          om = nm;
        }
        __hip_atomic_store(&pc[(size_t)c * k + j], packf2(om, os),
                           __ATOMIC_RELAXED, __HIP_MEMORY_SCOPE_AGENT);
      }
      if (wv == 0) {
        float x = (lane < cR) ? lu[lane] : -3.0e38f;
        float mm = x;
#pragma unroll
        for (int o = 32; o; o >>= 1) mm = fmaxf(mm, __shfl_xor(mm, o));
        float e = (lane < cR) ? expf(x - mm) : 0.f;
#pragma unroll
        for (int o = 32; o; o >>= 1) e += __shfl_xor(e, o);
        if (lane == 0)
          __hip_atomic_store(&pl[c], packf2(mm, e),
                             __ATOMIC_RELAXED, __HIP_MEMORY_SCOPE_AGENT);
      }
    }
    // ---- device-wide barrier (monotone counter; parity buffers make 1/iter safe) ----
    __syncthreads();
    __threadfence();
    if (tid == 0) {
      __hip_atomic_fetch_add(bar, 1u, __ATOMIC_ACQ_REL, __HIP_MEMORY_SCOPE_AGENT);
      unsigned tgt = (unsigned)gridDim.x * (unsigned)(m + 1);
      while (__hip_atomic_load(bar, __ATOMIC_ACQUIRE, __HIP_MEMORY_SCOPE_AGENT) < tgt)
        __builtin_amdgcn_s_sleep(8);
    }
    __syncthreads();
    __threadfence();
    if (active) {
      // combine col partials of own type -> V
      for (int j = tid; j < k; j += 256) {
        float mm = -3.0e38f, ss = 0.f;
        for (int q = 0; q < cN; q++) {
          u64 pk = __hip_atomic_load(&pc[(size_t)(cS + q) * k + j],
                                     __ATOMIC_RELAXED, __HIP_MEMORY_SCOPE_AGENT);
          float mq = __uint_as_float((unsigned)pk);
          float sq = __uint_as_float((unsigned)(pk >> 32));
          float nm = fmaxf(mm, mq);
          ss = ss * expf(mm - nm) + sq * expf(mq - nm);
          mm = nm;
        }
        V[j] = -(mm + logf(ss));
      }
      // combine all lu partials -> lvlast
      if (wv == 0) {
        float mm = -3.0e38f, ss = 0.f;
        for (int q = lane; q < NC; q += 64) {
          u64 pk = __hip_atomic_load(&pl[q], __ATOMIC_RELAXED, __HIP_MEMORY_SCOPE_AGENT);
          float mq = __uint_as_float((unsigned)pk);
          float sq = __uint_as_float((unsigned)(pk >> 32));
          float nm = fmaxf(mm, mq);
          ss = ss * expf(mm - nm) + sq * expf(mq - nm);
          mm = nm;
        }
#pragma unroll
        for (int o = 32; o; o >>= 1) {
          float mq = __shfl_xor(mm, o), sq = __shfl_xor(ss, o);
          float nm = fmaxf(mm, mq);
          ss = ss * expf(mm - nm) + sq * expf(mq - nm);
          mm = nm;
        }
        if (lane == 0) lvlast_sh = logf(tm_last) - (mm + logf(ss));
      }
    }
    __syncthreads();
  }
  if (active) {
    for (int r = tid; r < cR; r += 256) luF[s0 + r] = lu[r];
    if (c == cS)
      for (int j = tid; j < k; j += 256) VF[(size_t)t * k + j] = V[j];
  }
}

// epilogue: logits = log(exp(M+lu+V)+1e-8); T row = scatter into j*17+t, zeros elsewhere
__global__ __launch_bounds__(256) void k_epi(const float* __restrict__ Ms,
    const float* __restrict__ luF, const float* __restrict__ VF,
    const int* __restrict__ perm, const int* __restrict__ tys,
    float* __restrict__ out, int n, int k) {
  __shared__ float vals[KCAP];
  int r = blockIdx.x;
  int i = perm[r], t = tys[r];
  float lu = luF[r];
  const float* Mrow = Ms + (size_t)r * k;
  const float* Vrow = VF + (size_t)t * k;
  for (int j = threadIdx.x; j < k; j += 256) vals[j] = expf(Mrow[j] + lu + Vrow[j]);
  __syncthreads();
  float* lg = out + (size_t)i * k;
  for (int j = threadIdx.x; j < k; j += 256) lg[j] = logf(vals[j] + 1e-8f);
  int ns = k * NT;
  float* Trow = out + (size_t)n * k + (size_t)i * ns;
  if ((ns & 3) == 0 && (((size_t)n * k) & 3) == 0) {
    int n4 = ns >> 2;
    for (int g4 = threadIdx.x; g4 < n4; g4 += 256) {
      int o0 = g4 << 2;
      float v[4] = {0.f, 0.f, 0.f, 0.f};
#pragma unroll
      for (int s = 0; s < 4; s++) {
        int o = o0 + s;
        int j = o / NT;
        int tt = o - j * NT;
        if (tt == t) v[s] = vals[j];
      }
      *(float4*)(Trow + o0) = make_float4(v[0], v[1], v[2], v[3]);
    }
  } else {
    for (int o = threadIdx.x; o < ns; o += 256) {
      int j = o / NT;
      int tt = o - j * NT;
      Trow[o] = (tt == t) ? vals[j] : 0.f;
    }
  }
}

extern "C" void kernel_launch(void* const* d_in, const int* in_sizes, int n_in,
                              void* d_out, int out_size, void* d_ws, size_t ws_size,
                              hipStream_t stream) {
  const float* emb = (const float*)d_in[0];
  const float* W1  = (const float*)d_in[1];
  const float* b1  = (const float*)d_in[2];
  const float* P   = (const float*)d_in[3];
  const int*   jt  = (const int*)d_in[4];
  (void)n_in; (void)ws_size;

  const int n = in_sizes[4];
  const int H = in_sizes[2];
  const int D = in_sizes[1] / H;
  const int k = out_size / (n * (NT + 1));
  const int nslots = k * NT;
  const float tm_last = (float)((n - nslots) > 1 ? (n - nslots) : 1);
  const int NCmax = NT + (n + CH - 1) / CH;

  char* w = (char*)d_ws;
  size_t off = 0;
  auto take = [&](size_t bytes) -> char* {
    char* p = w + off;
    off = (off + bytes + 255) & ~(size_t)255;
    return p;
  };
  int*   meta = (int*)take(4096);
  int*   perm = (int*)take((size_t)n * 4);
  int*   tys  = (int*)take((size_t)n * 4);
  float* h    = (float*)take((size_t)n * H * 4);
  float* hsq  = (float*)take((size_t)n * 4);
  float* psq  = (float*)take((size_t)k * 4);
  float* Ms   = (float*)take((size_t)n * k * 4);
  u64*   pcol = (u64*)take((size_t)2 * NCmax * k * 8);
  u64*   plu  = (u64*)take((size_t)2 * NCmax * 8);
  float* luF  = (float*)take((size_t)n * 4);
  float* VF   = (float*)take((size_t)NT * k * 4);

  hipMemsetAsync(meta, 0, 4096, stream);
  k_hist<<<(n + 255) / 256, 256, 0, stream>>>(jt, n, meta);
  k_scatter<<<(n + 255) / 256, 256, 0, stream>>>(jt, n, meta, perm, tys);
  k_hgemm<<<dim3(n / 64, H / 64), dim3(256), 0, stream>>>(emb, W1, b1, h, n, D, H);
  k_norms<<<(n + k + 3) / 4, 256, 0, stream>>>(h, P, hsq, psq, n, H, k);
  k_msort<<<dim3(n / 64, (k + 63) / 64), dim3(256), 0, stream>>>(h, P, hsq, psq, perm, Ms, n, H, k);
  k_sink<<<NCmax, 256, 0, stream>>>(Ms, meta, pcol, plu, luF, VF, k, NCmax, tm_last);
  k_epi<<<n, 256, 0, stream>>>(Ms, luF, VF, perm, tys, (float*)d_out, n, k);
}

// Round 3
// 827.276 us; speedup vs baseline: 2.1629x; 2.1629x over previous
//
#include <hip/hip_runtime.h>
#include <math.h>

#define NT 17
#define CH 48
#define KCAP 300
#define NITER 30
#define NWAVE 8
// -1/tau * log2(e): sinkhorn runs in base-2 log domain
#define MSCALE2 28.853900817779268f

typedef unsigned long long u64;

// ---- meta layout (ints at ws start, zeroed each launch) ----
// [0..31]   typeCount
// [32..63]  typeOff
// [64..95]  scatterCnt
// [96]      doneFlag
// [98]      NC (number of real chunks)
// [128..127+4*NC] chunkMeta: 4 ints per chunk (type, startSortedRow, nRows, pad)
// [768..784] chunkStart[17] (first chunk id of type)
// [800..816] chunkCnt[17]
// [832+16q] barrier arrival counters, q=0..7 (64B apart)

__device__ inline u64 packf2(float m, float s) {
  return ((u64)__float_as_uint(s) << 32) | (u64)__float_as_uint(m);
}
__device__ inline float plo(u64 p) { return __uint_as_float((unsigned)p); }
__device__ inline float phi(u64 p) { return __uint_as_float((unsigned)(p >> 32)); }

__device__ inline float selu_f(float x) {
  const float scale = 1.0507009873554804934193349852946f;
  const float alpha = 1.6732632423543772848170429916717f;
  return x > 0.f ? scale * x : scale * alpha * expm1f(x);
}

__global__ void k_hist(const int* __restrict__ jt, int n, int* meta) {
  int i = blockIdx.x * 256 + threadIdx.x;
  if (i < n) atomicAdd(&meta[jt[i]], 1);
  __syncthreads();
  if (threadIdx.x == 0) {
    __threadfence();
    int d = atomicAdd(&meta[96], 1);
    if (d == (int)gridDim.x - 1) {
      int off = 0, nc = 0;
      for (int t = 0; t < NT; t++) {
        int c = __hip_atomic_load(&meta[t], __ATOMIC_RELAXED, __HIP_MEMORY_SCOPE_AGENT);
        meta[32 + t] = off;
        meta[768 + t] = nc;
        int ncs = (c + CH - 1) / CH;
        meta[800 + t] = ncs;
        int pos = off;
        for (int q = 0; q < ncs; q++) {
          int len = c - q * CH; if (len > CH) len = CH;
          meta[128 + 4 * nc + 0] = t;
          meta[128 + 4 * nc + 1] = pos;
          meta[128 + 4 * nc + 2] = len;
          nc++; pos += len;
        }
        off += c;
      }
      meta[98] = nc;
      __threadfence();
    }
  }
}

__global__ void k_scatter(const int* __restrict__ jt, int n, int* meta,
                          int* __restrict__ perm, int* __restrict__ tys) {
  int i = blockIdx.x * 256 + threadIdx.x;
  if (i < n) {
    int t = jt[i];
    int pos = meta[32 + t] + atomicAdd(&meta[64 + t], 1);
    perm[pos] = i;
    tys[pos] = t;
  }
}

// h = selu(emb @ W1 + b1)   (n x D) @ (D x H)
__global__ __launch_bounds__(256) void k_hgemm(const float* __restrict__ A,
    const float* __restrict__ B, const float* __restrict__ bias,
    float* __restrict__ C, int n, int D, int H) {
  __shared__ __align__(16) float As[16][68];
  __shared__ __align__(16) float Bs[16][68];
  int tid = threadIdx.x;
  int i0 = blockIdx.x * 64, j0 = blockIdx.y * 64;
  int tx = tid & 15, ty = tid >> 4;
  int aI = tid & 63, aK = (tid >> 6) << 2;
  int bJ = (tid & 15) << 2, bK = tid >> 4;
  float acc[4][4] = {};
  for (int k0 = 0; k0 < D; k0 += 16) {
    float4 av = *(const float4*)(A + (size_t)(i0 + aI) * D + k0 + aK);
    float4 bv = *(const float4*)(B + (size_t)(k0 + bK) * H + j0 + bJ);
    __syncthreads();
    As[aK + 0][aI] = av.x; As[aK + 1][aI] = av.y; As[aK + 2][aI] = av.z; As[aK + 3][aI] = av.w;
    *(float4*)(&Bs[bK][bJ]) = bv;
    __syncthreads();
#pragma unroll
    for (int kk = 0; kk < 16; kk++) {
      float4 a4 = *(float4*)(&As[kk][ty << 2]);
      float4 b4 = *(float4*)(&Bs[kk][tx << 2]);
      float aa[4] = {a4.x, a4.y, a4.z, a4.w};
      float bb[4] = {b4.x, b4.y, b4.z, b4.w};
#pragma unroll
      for (int p = 0; p < 4; p++)
#pragma unroll
        for (int q = 0; q < 4; q++)
          acc[p][q] = fmaf(aa[p], bb[q], acc[p][q]);
    }
  }
#pragma unroll
  for (int p = 0; p < 4; p++) {
    int i = i0 + (ty << 2) + p;
    float o[4];
#pragma unroll
    for (int q = 0; q < 4; q++) {
      int j = j0 + (tx << 2) + q;
      o[q] = selu_f(acc[p][q] + bias[j]);
    }
    *(float4*)(C + (size_t)i * H + j0 + (tx << 2)) = make_float4(o[0], o[1], o[2], o[3]);
  }
}

// row norms of h (n rows) and prototypes (k rows)
__global__ __launch_bounds__(256) void k_norms(const float* __restrict__ h,
    const float* __restrict__ P, float* __restrict__ hsq, float* __restrict__ psq,
    int n, int H, int k) {
  int wv = threadIdx.x >> 6, lane = threadIdx.x & 63;
  int idx = blockIdx.x * 4 + wv;
  const float* src; float* dst;
  if (idx < n) { src = h + (size_t)idx * H; dst = hsq + idx; }
  else if (idx < n + k) { int j = idx - n; src = P + (size_t)j * H; dst = psq + j; }
  else return;
  float s = 0.f;
  for (int d = lane * 4; d < H; d += 256) {
    float4 v = *(const float4*)(src + d);
    s += v.x * v.x + v.y * v.y + v.z * v.z + v.w * v.w;
  }
#pragma unroll
  for (int o = 32; o; o >>= 1) s += __shfl_xor(s, o);
  if (lane == 0) *dst = s;
}

// Ms[r][j] = -max(0, hsq+psq-2*dot)/tau * log2(e)  (base-2 domain), rows type-sorted
__global__ __launch_bounds__(256) void k_msort(const float* __restrict__ h,
    const float* __restrict__ P, const float* __restrict__ hsq,
    const float* __restrict__ psq, const int* __restrict__ perm,
    float* __restrict__ Ms, int n, int H, int k) {
  __shared__ __align__(16) float As[16][68];
  __shared__ __align__(16) float Bs[16][68];
  __shared__ int gIdx[64];
  int tid = threadIdx.x;
  int i0 = blockIdx.x * 64, j0 = blockIdx.y * 64;
  if (tid < 64) gIdx[tid] = perm[i0 + tid];
  __syncthreads();
  int tx = tid & 15, ty = tid >> 4;
  int aI = tid & 63, aK = (tid >> 6) << 2;
  int gA = gIdx[aI];
  bool bok = (j0 + aI) < k;
  const float* bRow = P + (size_t)(j0 + (bok ? aI : 0)) * H;
  float acc[4][4] = {};
  for (int k0 = 0; k0 < H; k0 += 16) {
    float4 av = *(const float4*)(h + (size_t)gA * H + k0 + aK);
    float4 bv = *(const float4*)(bRow + k0 + aK);
    __syncthreads();
    As[aK + 0][aI] = av.x; As[aK + 1][aI] = av.y; As[aK + 2][aI] = av.z; As[aK + 3][aI] = av.w;
    Bs[aK + 0][aI] = bv.x; Bs[aK + 1][aI] = bv.y; Bs[aK + 2][aI] = bv.z; Bs[aK + 3][aI] = bv.w;
    __syncthreads();
#pragma unroll
    for (int kk = 0; kk < 16; kk++) {
      float4 a4 = *(float4*)(&As[kk][ty << 2]);
      float4 b4 = *(float4*)(&Bs[kk][tx << 2]);
      float aa[4] = {a4.x, a4.y, a4.z, a4.w};
      float bb[4] = {b4.x, b4.y, b4.z, b4.w};
#pragma unroll
      for (int p = 0; p < 4; p++)
#pragma unroll
        for (int q = 0; q < 4; q++)
          acc[p][q] = fmaf(aa[p], bb[q], acc[p][q]);
    }
  }
#pragma unroll
  for (int p = 0; p < 4; p++) {
    int rr = (ty << 2) + p;
    int r = i0 + rr;
    float hq = hsq[gIdx[rr]];
#pragma unroll
    for (int q = 0; q < 4; q++) {
      int j = j0 + (tx << 2) + q;
      if (j < k) {
        float d2 = hq + psq[j] - 2.f * acc[p][q];
        d2 = fmaxf(d2, 0.f);
        Ms[(size_t)r * k + j] = -d2 * MSCALE2;
      }
    }
  }
}

// Persistent Sinkhorn, base-2 log domain. One type-pure <=48-row chunk per block.
// M held in LDS col-major stride 49 (conflict-free both directions).
__global__ __launch_bounds__(512) void k_sink(const float* __restrict__ Ms,
    int* __restrict__ meta, u64* __restrict__ pcol, u64* __restrict__ plu,
    float* __restrict__ luF, float* __restrict__ VF,
    int k, int NCmax, float l2tm) {
  __shared__ float Mc[KCAP * 49];
  __shared__ float V[KCAP];
  __shared__ float lu[CH];
  __shared__ float lvl_sh;
  int tid = threadIdx.x, lane = tid & 63, wv = tid >> 6;
  int c = blockIdx.x;
  int NC = meta[98];
  bool active = (c < NC);
  int t = 0, s0 = 0, cR = 0, cS = 0, cN = 0;
  if (active) {
    t  = meta[128 + 4 * c + 0];
    s0 = meta[128 + 4 * c + 1];
    cR = meta[128 + 4 * c + 2];
    cS = meta[768 + t];
    cN = meta[800 + t];
  }
  if (active) {
    const float* src = Ms + (size_t)s0 * k;
    for (int r = wv; r < cR; r += NWAVE)
      for (int j = lane; j < k; j += 64)
        Mc[j * 49 + r] = src[(size_t)r * k + j];
  }
  for (int j = tid; j < k; j += 512) V[j] = 0.f;
  if (tid == 0) lvl_sh = 0.f;
  __syncthreads();

  for (int m = 0; m < NITER; m++) {
    u64* pc = pcol + (size_t)(m & 1) * NCmax * k;
    u64* pl = plu + (size_t)(m & 1) * NCmax;
    float lvl = lvl_sh;
    if (active) {
      // ---- row pass: wave per row, two-pass register LSE2 ----
      for (int r = wv; r < cR; r += NWAVE) {
        float xv[5];
        int cnt = 0;
        for (int j = lane; j < k; j += 64) { xv[cnt++] = Mc[j * 49 + r] + V[j]; }
        float xm = -3.0e38f;
        for (int q = 0; q < cnt; q++) xm = fmaxf(xm, xv[q]);
        if (lane == 0) xm = fmaxf(xm, lvl);
#pragma unroll
        for (int o = 32; o; o >>= 1) xm = fmaxf(xm, __shfl_xor(xm, o));
        float s = 0.f;
        for (int q = 0; q < cnt; q++) s += exp2f(xv[q] - xm);
        if (lane == 0) s += exp2f(lvl - xm);
#pragma unroll
        for (int o = 32; o; o >>= 1) s += __shfl_xor(s, o);
        if (lane == 0) lu[r] = -(xm + __log2f(s));
      }
    }
    __syncthreads();
    if (active) {
      // ---- column partials: thread per column, two-pass 4-way unrolled ----
      for (int j = tid; j < k; j += 512) {
        const float* col = &Mc[j * 49];
        float m0 = -3.0e38f, m1 = -3.0e38f, m2 = -3.0e38f, m3 = -3.0e38f;
        int r = 0;
        for (; r + 4 <= cR; r += 4) {
          m0 = fmaxf(m0, col[r + 0] + lu[r + 0]);
          m1 = fmaxf(m1, col[r + 1] + lu[r + 1]);
          m2 = fmaxf(m2, col[r + 2] + lu[r + 2]);
          m3 = fmaxf(m3, col[r + 3] + lu[r + 3]);
        }
        for (; r < cR; r++) m0 = fmaxf(m0, col[r] + lu[r]);
        float mm = fmaxf(fmaxf(m0, m1), fmaxf(m2, m3));
        float sa = 0.f, sb = 0.f, sc = 0.f, sd = 0.f;
        r = 0;
        for (; r + 4 <= cR; r += 4) {
          sa += exp2f(col[r + 0] + lu[r + 0] - mm);
          sb += exp2f(col[r + 1] + lu[r + 1] - mm);
          sc += exp2f(col[r + 2] + lu[r + 2] - mm);
          sd += exp2f(col[r + 3] + lu[r + 3] - mm);
        }
        for (; r < cR; r++) sa += exp2f(col[r] + lu[r] - mm);
        float ss = (sa + sb) + (sc + sd);
        __hip_atomic_store(&pc[(size_t)c * k + j], packf2(mm, ss),
                           __ATOMIC_RELAXED, __HIP_MEMORY_SCOPE_AGENT);
      }
      if (wv == 0) {
        // chunk-level lse2 of lu -> pl[c]
        float x = (lane < cR) ? lu[lane] : -3.0e38f;
        float mm = x;
#pragma unroll
        for (int o = 32; o; o >>= 1) mm = fmaxf(mm, __shfl_xor(mm, o));
        float e = (lane < cR) ? exp2f(x - mm) : 0.f;
#pragma unroll
        for (int o = 32; o; o >>= 1) e += __shfl_xor(e, o);
        if (lane == 0)
          __hip_atomic_store(&pl[c], packf2(mm, e),
                             __ATOMIC_RELAXED, __HIP_MEMORY_SCOPE_AGENT);
      }
    }
    // ---- device barrier: 8 spread arrival counters, tid0 polls sum ----
    __syncthreads();
    if (tid == 0) {
      __hip_atomic_fetch_add((unsigned*)&meta[832 + 16 * (c & 7)], 1u,
                             __ATOMIC_RELEASE, __HIP_MEMORY_SCOPE_AGENT);
      unsigned tgt = (unsigned)gridDim.x * (unsigned)(m + 1);
      for (;;) {
        unsigned s = 0;
#pragma unroll
        for (int q = 0; q < 8; q++)
          s += __hip_atomic_load((unsigned*)&meta[832 + 16 * q],
                                 __ATOMIC_RELAXED, __HIP_MEMORY_SCOPE_AGENT);
        if (s >= tgt) break;
        __builtin_amdgcn_s_sleep(2);
      }
      __builtin_amdgcn_fence(__ATOMIC_ACQUIRE, "agent");
    }
    __syncthreads();
    if (active) {
      // ---- combine col partials of own type -> V (prefetch then merge) ----
      for (int j = tid; j < k; j += 512) {
        u64 pk[12];
#pragma unroll
        for (int q = 0; q < 12; q++)
          pk[q] = (q < cN)
              ? __hip_atomic_load(&pc[(size_t)(cS + q) * k + j],
                                  __ATOMIC_RELAXED, __HIP_MEMORY_SCOPE_AGENT)
              : packf2(-3.0e38f, 0.f);
        float mm = -3.0e38f;
#pragma unroll
        for (int q = 0; q < 12; q++) mm = fmaxf(mm, plo(pk[q]));
        float ss = 0.f;
#pragma unroll
        for (int q = 0; q < 12; q++) ss += phi(pk[q]) * exp2f(plo(pk[q]) - mm);
        V[j] = -(mm + __log2f(ss));
      }
      // ---- combine all lu partials -> lvlast (wave 7, prefetch 3) ----
      if (wv == NWAVE - 1) {
        u64 a0 = (lane < NC)
            ? __hip_atomic_load(&pl[lane], __ATOMIC_RELAXED, __HIP_MEMORY_SCOPE_AGENT)
            : packf2(-3.0e38f, 0.f);
        u64 a1 = (lane + 64 < NC)
            ? __hip_atomic_load(&pl[lane + 64], __ATOMIC_RELAXED, __HIP_MEMORY_SCOPE_AGENT)
            : packf2(-3.0e38f, 0.f);
        u64 a2 = (lane + 128 < NC)
            ? __hip_atomic_load(&pl[lane + 128], __ATOMIC_RELAXED, __HIP_MEMORY_SCOPE_AGENT)
            : packf2(-3.0e38f, 0.f);
        float mm = fmaxf(fmaxf(plo(a0), plo(a1)), plo(a2));
        float ss = phi(a0) * exp2f(plo(a0) - mm) + phi(a1) * exp2f(plo(a1) - mm) +
                   phi(a2) * exp2f(plo(a2) - mm);
#pragma unroll
        for (int o = 32; o; o >>= 1) {
          float mq = __shfl_xor(mm, o), sq = __shfl_xor(ss, o);
          float nm = fmaxf(mm, mq);
          ss = ss * exp2f(mm - nm) + sq * exp2f(mq - nm);
          mm = nm;
        }
        if (lane == 0) lvl_sh = l2tm - (mm + __log2f(ss));
      }
    }
    __syncthreads();
  }
  if (active) {
    for (int r = tid; r < cR; r += 512) luF[s0 + r] = lu[r];
    if (c == cS)
      for (int j = tid; j < k; j += 512) VF[(size_t)t * k + j] = V[j];
  }
}

// epilogue (base-2): logits = log(exp2(M+lu+V)+1e-8); T row scatter into j*17+t
__global__ __launch_bounds__(256) void k_epi(const float* __restrict__ Ms,
    const float* __restrict__ luF, const float* __restrict__ VF,
    const int* __restrict__ perm, const int* __restrict__ tys,
    float* __restrict__ out, int n, int k) {
  __shared__ float vals[KCAP];
  int r = blockIdx.x;
  int i = perm[r], t = tys[r];
  float lu = luF[r];
  const float* Mrow = Ms + (size_t)r * k;
  const float* Vrow = VF + (size_t)t * k;
  for (int j = threadIdx.x; j < k; j += 256) vals[j] = exp2f(Mrow[j] + lu + Vrow[j]);
  __syncthreads();
  float* lg = out + (size_t)i * k;
  for (int j = threadIdx.x; j < k; j += 256) lg[j] = logf(vals[j] + 1e-8f);
  int ns = k * NT;
  float* Trow = out + (size_t)n * k + (size_t)i * ns;
  if ((ns & 3) == 0 && (((size_t)n * k) & 3) == 0) {
    int n4 = ns >> 2;
    for (int g4 = threadIdx.x; g4 < n4; g4 += 256) {
      int o0 = g4 << 2;
      float v[4] = {0.f, 0.f, 0.f, 0.f};
#pragma unroll
      for (int s = 0; s < 4; s++) {
        int o = o0 + s;
        int j = o / NT;
        int tt = o - j * NT;
        if (tt == t) v[s] = vals[j];
      }
      *(float4*)(Trow + o0) = make_float4(v[0], v[1], v[2], v[3]);
    }
  } else {
    for (int o = threadIdx.x; o < ns; o += 256) {
      int j = o / NT;
      int tt = o - j * NT;
      Trow[o] = (tt == t) ? vals[j] : 0.f;
    }
  }
}

extern "C" void kernel_launch(void* const* d_in, const int* in_sizes, int n_in,
                              void* d_out, int out_size, void* d_ws, size_t ws_size,
                              hipStream_t stream) {
  const float* emb = (const float*)d_in[0];
  const float* W1  = (const float*)d_in[1];
  const float* b1  = (const float*)d_in[2];
  const float* P   = (const float*)d_in[3];
  const int*   jt  = (const int*)d_in[4];
  (void)n_in; (void)ws_size;

  const int n = in_sizes[4];
  const int H = in_sizes[2];
  const int D = in_sizes[1] / H;
  const int k = out_size / (n * (NT + 1));
  const int nslots = k * NT;
  const float tm_last = (float)((n - nslots) > 1 ? (n - nslots) : 1);
  const float l2tm = log2f(tm_last);
  const int NCmax = NT + (n + CH - 1) / CH;

  char* w = (char*)d_ws;
  size_t off = 0;
  auto take = [&](size_t bytes) -> char* {
    char* p = w + off;
    off = (off + bytes + 255) & ~(size_t)255;
    return p;
  };
  int*   meta = (int*)take(4096);
  int*   perm = (int*)take((size_t)n * 4);
  int*   tys  = (int*)take((size_t)n * 4);
  float* h    = (float*)take((size_t)n * H * 4);
  float* hsq  = (float*)take((size_t)n * 4);
  float* psq  = (float*)take((size_t)k * 4);
  float* Ms   = (float*)take((size_t)n * k * 4);
  u64*   pcol = (u64*)take((size_t)2 * NCmax * k * 8);
  u64*   plu  = (u64*)take((size_t)2 * NCmax * 8);
  float* luF  = (float*)take((size_t)n * 4);
  float* VF   = (float*)take((size_t)NT * k * 4);

  (void)hipMemsetAsync(meta, 0, 4096, stream);
  k_hist<<<(n + 255) / 256, 256, 0, stream>>>(jt, n, meta);
  k_scatter<<<(n + 255) / 256, 256, 0, stream>>>(jt, n, meta, perm, tys);
  k_hgemm<<<dim3(n / 64, H / 64), dim3(256), 0, stream>>>(emb, W1, b1, h, n, D, H);
  k_norms<<<(n + k + 3) / 4, 256, 0, stream>>>(h, P, hsq, psq, n, H, k);
  k_msort<<<dim3(n / 64, (k + 63) / 64), dim3(256), 0, stream>>>(h, P, hsq, psq, perm, Ms, n, H, k);
  k_sink<<<NCmax, 512, 0, stream>>>(Ms, meta, pcol, plu, luF, VF, k, NCmax, l2tm);
  k_epi<<<n, 256, 0, stream>>>(Ms, luF, VF, perm, tys, (float*)d_out, n, k);
}

// Round 4
// 739.965 us; speedup vs baseline: 2.4181x; 1.1180x over previous
//
#include <hip/hip_runtime.h>
#include <math.h>

#define NT 17
#define CH 48
#define KCAP 300
#define NITER 30
#define NWAVE 8
// -1/tau * log2(e): sinkhorn runs in base-2 log domain
#define MSCALE2 28.853900817779268f

typedef unsigned long long u64;

// ---- meta layout (ints at ws start, zeroed each launch) ----
// [0..31]   typeCount
// [32..63]  typeOff
// [64..95]  scatterCnt
// [96]      doneFlag
// [98]      NC (number of real chunks)
// [99]      barrier epoch broadcast
// [128..127+4*NC] chunkMeta: 4 ints per chunk (type, startSortedRow, nRows, pad)
// [768..784] chunkStart[17] (first chunk id of type)
// [800..816] chunkCnt[17]
// [832+16q] barrier arrival counters, q=0..7 (64B apart)

__device__ inline u64 packf2(float m, float s) {
  return ((u64)__float_as_uint(s) << 32) | (u64)__float_as_uint(m);
}
__device__ inline float plo(u64 p) { return __uint_as_float((unsigned)p); }
__device__ inline float phi(u64 p) { return __uint_as_float((unsigned)(p >> 32)); }

__device__ inline float selu_f(float x) {
  const float scale = 1.0507009873554804934193349852946f;
  const float alpha = 1.6732632423543772848170429916717f;
  return x > 0.f ? scale * x : scale * alpha * expm1f(x);
}

__global__ void k_hist(const int* __restrict__ jt, int n, int* meta) {
  int i = blockIdx.x * 256 + threadIdx.x;
  if (i < n) atomicAdd(&meta[jt[i]], 1);
  __syncthreads();
  if (threadIdx.x == 0) {
    __threadfence();
    int d = atomicAdd(&meta[96], 1);
    if (d == (int)gridDim.x - 1) {
      int off = 0, nc = 0;
      for (int t = 0; t < NT; t++) {
        int c = __hip_atomic_load(&meta[t], __ATOMIC_RELAXED, __HIP_MEMORY_SCOPE_AGENT);
        meta[32 + t] = off;
        meta[768 + t] = nc;
        int ncs = (c + CH - 1) / CH;
        meta[800 + t] = ncs;
        int pos = off;
        for (int q = 0; q < ncs; q++) {
          int len = c - q * CH; if (len > CH) len = CH;
          meta[128 + 4 * nc + 0] = t;
          meta[128 + 4 * nc + 1] = pos;
          meta[128 + 4 * nc + 2] = len;
          nc++; pos += len;
        }
        off += c;
      }
      meta[98] = nc;
      __threadfence();
    }
  }
}

__global__ void k_scatter(const int* __restrict__ jt, int n, int* meta,
                          int* __restrict__ perm, int* __restrict__ tys) {
  int i = blockIdx.x * 256 + threadIdx.x;
  if (i < n) {
    int t = jt[i];
    int pos = meta[32 + t] + atomicAdd(&meta[64 + t], 1);
    perm[pos] = i;
    tys[pos] = t;
  }
}

// h = selu(emb @ W1 + b1)   (n x D) @ (D x H)
__global__ __launch_bounds__(256) void k_hgemm(const float* __restrict__ A,
    const float* __restrict__ B, const float* __restrict__ bias,
    float* __restrict__ C, int n, int D, int H) {
  __shared__ __align__(16) float As[16][68];
  __shared__ __align__(16) float Bs[16][68];
  int tid = threadIdx.x;
  int i0 = blockIdx.x * 64, j0 = blockIdx.y * 64;
  int tx = tid & 15, ty = tid >> 4;
  int aI = tid & 63, aK = (tid >> 6) << 2;
  int bJ = (tid & 15) << 2, bK = tid >> 4;
  float acc[4][4] = {};
  for (int k0 = 0; k0 < D; k0 += 16) {
    float4 av = *(const float4*)(A + (size_t)(i0 + aI) * D + k0 + aK);
    float4 bv = *(const float4*)(B + (size_t)(k0 + bK) * H + j0 + bJ);
    __syncthreads();
    As[aK + 0][aI] = av.x; As[aK + 1][aI] = av.y; As[aK + 2][aI] = av.z; As[aK + 3][aI] = av.w;
    *(float4*)(&Bs[bK][bJ]) = bv;
    __syncthreads();
#pragma unroll
    for (int kk = 0; kk < 16; kk++) {
      float4 a4 = *(float4*)(&As[kk][ty << 2]);
      float4 b4 = *(float4*)(&Bs[kk][tx << 2]);
      float aa[4] = {a4.x, a4.y, a4.z, a4.w};
      float bb[4] = {b4.x, b4.y, b4.z, b4.w};
#pragma unroll
      for (int p = 0; p < 4; p++)
#pragma unroll
        for (int q = 0; q < 4; q++)
          acc[p][q] = fmaf(aa[p], bb[q], acc[p][q]);
    }
  }
#pragma unroll
  for (int p = 0; p < 4; p++) {
    int i = i0 + (ty << 2) + p;
    float o[4];
#pragma unroll
    for (int q = 0; q < 4; q++) {
      int j = j0 + (tx << 2) + q;
      o[q] = selu_f(acc[p][q] + bias[j]);
    }
    *(float4*)(C + (size_t)i * H + j0 + (tx << 2)) = make_float4(o[0], o[1], o[2], o[3]);
  }
}

// row norms of h (n rows) and prototypes (k rows)
__global__ __launch_bounds__(256) void k_norms(const float* __restrict__ h,
    const float* __restrict__ P, float* __restrict__ hsq, float* __restrict__ psq,
    int n, int H, int k) {
  int wv = threadIdx.x >> 6, lane = threadIdx.x & 63;
  int idx = blockIdx.x * 4 + wv;
  const float* src; float* dst;
  if (idx < n) { src = h + (size_t)idx * H; dst = hsq + idx; }
  else if (idx < n + k) { int j = idx - n; src = P + (size_t)j * H; dst = psq + j; }
  else return;
  float s = 0.f;
  for (int d = lane * 4; d < H; d += 256) {
    float4 v = *(const float4*)(src + d);
    s += v.x * v.x + v.y * v.y + v.z * v.z + v.w * v.w;
  }
#pragma unroll
  for (int o = 32; o; o >>= 1) s += __shfl_xor(s, o);
  if (lane == 0) *dst = s;
}

// Ms[r][j] = -max(0, hsq+psq-2*dot)/tau * log2(e)  (base-2 domain), rows type-sorted
__global__ __launch_bounds__(256) void k_msort(const float* __restrict__ h,
    const float* __restrict__ P, const float* __restrict__ hsq,
    const float* __restrict__ psq, const int* __restrict__ perm,
    float* __restrict__ Ms, int n, int H, int k) {
  __shared__ __align__(16) float As[16][68];
  __shared__ __align__(16) float Bs[16][68];
  __shared__ int gIdx[64];
  int tid = threadIdx.x;
  int i0 = blockIdx.x * 64, j0 = blockIdx.y * 64;
  if (tid < 64) gIdx[tid] = perm[i0 + tid];
  __syncthreads();
  int tx = tid & 15, ty = tid >> 4;
  int aI = tid & 63, aK = (tid >> 6) << 2;
  int gA = gIdx[aI];
  bool bok = (j0 + aI) < k;
  const float* bRow = P + (size_t)(j0 + (bok ? aI : 0)) * H;
  float acc[4][4] = {};
  for (int k0 = 0; k0 < H; k0 += 16) {
    float4 av = *(const float4*)(h + (size_t)gA * H + k0 + aK);
    float4 bv = *(const float4*)(bRow + k0 + aK);
    __syncthreads();
    As[aK + 0][aI] = av.x; As[aK + 1][aI] = av.y; As[aK + 2][aI] = av.z; As[aK + 3][aI] = av.w;
    Bs[aK + 0][aI] = bv.x; Bs[aK + 1][aI] = bv.y; Bs[aK + 2][aI] = bv.z; Bs[aK + 3][aI] = bv.w;
    __syncthreads();
#pragma unroll
    for (int kk = 0; kk < 16; kk++) {
      float4 a4 = *(float4*)(&As[kk][ty << 2]);
      float4 b4 = *(float4*)(&Bs[kk][tx << 2]);
      float aa[4] = {a4.x, a4.y, a4.z, a4.w};
      float bb[4] = {b4.x, b4.y, b4.z, b4.w};
#pragma unroll
      for (int p = 0; p < 4; p++)
#pragma unroll
        for (int q = 0; q < 4; q++)
          acc[p][q] = fmaf(aa[p], bb[q], acc[p][q]);
    }
  }
#pragma unroll
  for (int p = 0; p < 4; p++) {
    int rr = (ty << 2) + p;
    int r = i0 + rr;
    float hq = hsq[gIdx[rr]];
#pragma unroll
    for (int q = 0; q < 4; q++) {
      int j = j0 + (tx << 2) + q;
      if (j < k) {
        float d2 = hq + psq[j] - 2.f * acc[p][q];
        d2 = fmaxf(d2, 0.f);
        Ms[(size_t)r * k + j] = -d2 * MSCALE2;
      }
    }
  }
}

// Persistent Sinkhorn, base-2 log domain. One type-pure <=48-row chunk per block.
// M held in LDS col-major stride 49 (conflict-free both directions).
// Cross-block exchange purely via agent-scope relaxed atomics (write-through,
// L2-bypassing) — NO acquire/release fences, so no buffer_wbl2/buffer_inv.
__global__ __launch_bounds__(512) void k_sink(const float* __restrict__ Ms,
    int* __restrict__ meta, u64* __restrict__ pcol, u64* __restrict__ plu,
    float* __restrict__ luF, float* __restrict__ VF,
    int k, int NCmax, float l2tm) {
  __shared__ float Mc[KCAP * 49];
  __shared__ float V[KCAP];
  __shared__ float lu[CH];
  __shared__ float lvl_sh;
  int tid = threadIdx.x, lane = tid & 63, wv = tid >> 6;
  int c = blockIdx.x;
  int NC = meta[98];
  bool active = (c < NC);
  int t = 0, s0 = 0, cR = 0, cS = 0, cN = 0;
  if (active) {
    t  = meta[128 + 4 * c + 0];
    s0 = meta[128 + 4 * c + 1];
    cR = meta[128 + 4 * c + 2];
    cS = meta[768 + t];
    cN = meta[800 + t];
  }
  if (active) {
    const float* src = Ms + (size_t)s0 * k;
    for (int r = wv; r < cR; r += NWAVE)
      for (int j = lane; j < k; j += 64)
        Mc[j * 49 + r] = src[(size_t)r * k + j];
  }
  for (int j = tid; j < k; j += 512) V[j] = 0.f;
  if (tid == 0) lvl_sh = 0.f;
  __syncthreads();

  for (int m = 0; m < NITER; m++) {
    u64* pc = pcol + (size_t)(m & 1) * NCmax * k;
    u64* pl = plu + (size_t)(m & 1) * NCmax;
    float lvl = lvl_sh;
    if (active) {
      // ---- row pass: wave per row, two-pass register LSE2 ----
      for (int r = wv; r < cR; r += NWAVE) {
        float xv[5];
        int cnt = 0;
        for (int j = lane; j < k; j += 64) { xv[cnt++] = Mc[j * 49 + r] + V[j]; }
        float xm = -3.0e38f;
        for (int q = 0; q < cnt; q++) xm = fmaxf(xm, xv[q]);
        if (lane == 0) xm = fmaxf(xm, lvl);
#pragma unroll
        for (int o = 32; o; o >>= 1) xm = fmaxf(xm, __shfl_xor(xm, o));
        float s = 0.f;
        for (int q = 0; q < cnt; q++) s += exp2f(xv[q] - xm);
        if (lane == 0) s += exp2f(lvl - xm);
#pragma unroll
        for (int o = 32; o; o >>= 1) s += __shfl_xor(s, o);
        if (lane == 0) lu[r] = -(xm + __log2f(s));
      }
    }
    __syncthreads();
    if (active) {
      // ---- column partials: thread per column, two-pass 4-way unrolled ----
      for (int j = tid; j < k; j += 512) {
        const float* col = &Mc[j * 49];
        float m0 = -3.0e38f, m1 = -3.0e38f, m2 = -3.0e38f, m3 = -3.0e38f;
        int r = 0;
        for (; r + 4 <= cR; r += 4) {
          m0 = fmaxf(m0, col[r + 0] + lu[r + 0]);
          m1 = fmaxf(m1, col[r + 1] + lu[r + 1]);
          m2 = fmaxf(m2, col[r + 2] + lu[r + 2]);
          m3 = fmaxf(m3, col[r + 3] + lu[r + 3]);
        }
        for (; r < cR; r++) m0 = fmaxf(m0, col[r] + lu[r]);
        float mm = fmaxf(fmaxf(m0, m1), fmaxf(m2, m3));
        float sa = 0.f, sb = 0.f, sc = 0.f, sd = 0.f;
        r = 0;
        for (; r + 4 <= cR; r += 4) {
          sa += exp2f(col[r + 0] + lu[r + 0] - mm);
          sb += exp2f(col[r + 1] + lu[r + 1] - mm);
          sc += exp2f(col[r + 2] + lu[r + 2] - mm);
          sd += exp2f(col[r + 3] + lu[r + 3] - mm);
        }
        for (; r < cR; r++) sa += exp2f(col[r] + lu[r] - mm);
        float ss = (sa + sb) + (sc + sd);
        __hip_atomic_store(&pc[(size_t)c * k + j], packf2(mm, ss),
                           __ATOMIC_RELAXED, __HIP_MEMORY_SCOPE_AGENT);
      }
      if (wv == 0) {
        // chunk-level lse2 of lu -> pl[c]
        float x = (lane < cR) ? lu[lane] : -3.0e38f;
        float mm = x;
#pragma unroll
        for (int o = 32; o; o >>= 1) mm = fmaxf(mm, __shfl_xor(mm, o));
        float e = (lane < cR) ? exp2f(x - mm) : 0.f;
#pragma unroll
        for (int o = 32; o; o >>= 1) e += __shfl_xor(e, o);
        if (lane == 0)
          __hip_atomic_store(&pl[c], packf2(mm, e),
                             __ATOMIC_RELAXED, __HIP_MEMORY_SCOPE_AGENT);
      }
    }
    // ---- fence-free device barrier ----
    // arrivals: relaxed adds on 8 spread counters (after draining own stores);
    // block 0 detects, broadcasts epoch; others poll the single epoch word.
    __syncthreads();
    if (tid == 0) {
      unsigned ep = (unsigned)(m + 1);
      __atomic_signal_fence(__ATOMIC_SEQ_CST);
      __builtin_amdgcn_s_waitcnt(0);  // own pc/pl stores globally visible
      __atomic_signal_fence(__ATOMIC_SEQ_CST);
      __hip_atomic_fetch_add((unsigned*)&meta[832 + 16 * (c & 7)], 1u,
                             __ATOMIC_RELAXED, __HIP_MEMORY_SCOPE_AGENT);
      if (c == 0) {
        unsigned tgt = (unsigned)gridDim.x * ep;
        for (;;) {
          unsigned s = 0;
#pragma unroll
          for (int q = 0; q < 8; q++)
            s += __hip_atomic_load((unsigned*)&meta[832 + 16 * q],
                                   __ATOMIC_RELAXED, __HIP_MEMORY_SCOPE_AGENT);
          if (s >= tgt) break;
          __builtin_amdgcn_s_sleep(1);
        }
        __hip_atomic_store((unsigned*)&meta[99], ep,
                           __ATOMIC_RELAXED, __HIP_MEMORY_SCOPE_AGENT);
      } else {
        while (__hip_atomic_load((unsigned*)&meta[99],
                                 __ATOMIC_RELAXED, __HIP_MEMORY_SCOPE_AGENT) < ep)
          __builtin_amdgcn_s_sleep(2);
      }
      __atomic_signal_fence(__ATOMIC_SEQ_CST);
    }
    __syncthreads();
    if (active) {
      // ---- combine col partials of own type -> V (prefetch then merge) ----
      for (int j = tid; j < k; j += 512) {
        u64 pk[12];
#pragma unroll
        for (int q = 0; q < 12; q++)
          pk[q] = (q < cN)
              ? __hip_atomic_load(&pc[(size_t)(cS + q) * k + j],
                                  __ATOMIC_RELAXED, __HIP_MEMORY_SCOPE_AGENT)
              : packf2(-3.0e38f, 0.f);
        float mm = -3.0e38f;
#pragma unroll
        for (int q = 0; q < 12; q++) mm = fmaxf(mm, plo(pk[q]));
        float ss = 0.f;
#pragma unroll
        for (int q = 0; q < 12; q++) ss += phi(pk[q]) * exp2f(plo(pk[q]) - mm);
        V[j] = -(mm + __log2f(ss));
      }
      // ---- combine all lu partials -> lvlast (wave 7, prefetch 3) ----
      if (wv == NWAVE - 1) {
        u64 a0 = (lane < NC)
            ? __hip_atomic_load(&pl[lane], __ATOMIC_RELAXED, __HIP_MEMORY_SCOPE_AGENT)
            : packf2(-3.0e38f, 0.f);
        u64 a1 = (lane + 64 < NC)
            ? __hip_atomic_load(&pl[lane + 64], __ATOMIC_RELAXED, __HIP_MEMORY_SCOPE_AGENT)
            : packf2(-3.0e38f, 0.f);
        u64 a2 = (lane + 128 < NC)
            ? __hip_atomic_load(&pl[lane + 128], __ATOMIC_RELAXED, __HIP_MEMORY_SCOPE_AGENT)
            : packf2(-3.0e38f, 0.f);
        float mm = fmaxf(fmaxf(plo(a0), plo(a1)), plo(a2));
        float ss = phi(a0) * exp2f(plo(a0) - mm) + phi(a1) * exp2f(plo(a1) - mm) +
                   phi(a2) * exp2f(plo(a2) - mm);
#pragma unroll
        for (int o = 32; o; o >>= 1) {
          float mq = __shfl_xor(mm, o), sq = __shfl_xor(ss, o);
          float nm = fmaxf(mm, mq);
          ss = ss * exp2f(mm - nm) + sq * exp2f(mq - nm);
          mm = nm;
        }
        if (lane == 0) lvl_sh = l2tm - (mm + __log2f(ss));
      }
    }
    __syncthreads();
  }
  if (active) {
    for (int r = tid; r < cR; r += 512) luF[s0 + r] = lu[r];
    if (c == cS)
      for (int j = tid; j < k; j += 512) VF[(size_t)t * k + j] = V[j];
  }
}

// epilogue (base-2): logits = log(exp2(M+lu+V)+1e-8); T row scatter into j*17+t
__global__ __launch_bounds__(256) void k_epi(const float* __restrict__ Ms,
    const float* __restrict__ luF, const float* __restrict__ VF,
    const int* __restrict__ perm, const int* __restrict__ tys,
    float* __restrict__ out, int n, int k) {
  __shared__ float vals[KCAP];
  int r = blockIdx.x;
  int i = perm[r], t = tys[r];
  float lu = luF[r];
  const float* Mrow = Ms + (size_t)r * k;
  const float* Vrow = VF + (size_t)t * k;
  for (int j = threadIdx.x; j < k; j += 256) vals[j] = exp2f(Mrow[j] + lu + Vrow[j]);
  __syncthreads();
  float* lg = out + (size_t)i * k;
  for (int j = threadIdx.x; j < k; j += 256) lg[j] = logf(vals[j] + 1e-8f);
  int ns = k * NT;
  float* Trow = out + (size_t)n * k + (size_t)i * ns;
  if ((ns & 3) == 0 && (((size_t)n * k) & 3) == 0) {
    int n4 = ns >> 2;
    for (int g4 = threadIdx.x; g4 < n4; g4 += 256) {
      int o0 = g4 << 2;
      float v[4] = {0.f, 0.f, 0.f, 0.f};
#pragma unroll
      for (int s = 0; s < 4; s++) {
        int o = o0 + s;
        int j = o / NT;
        int tt = o - j * NT;
        if (tt == t) v[s] = vals[j];
      }
      *(float4*)(Trow + o0) = make_float4(v[0], v[1], v[2], v[3]);
    }
  } else {
    for (int o = threadIdx.x; o < ns; o += 256) {
      int j = o / NT;
      int tt = o - j * NT;
      Trow[o] = (tt == t) ? vals[j] : 0.f;
    }
  }
}

extern "C" void kernel_launch(void* const* d_in, const int* in_sizes, int n_in,
                              void* d_out, int out_size, void* d_ws, size_t ws_size,
                              hipStream_t stream) {
  const float* emb = (const float*)d_in[0];
  const float* W1  = (const float*)d_in[1];
  const float* b1  = (const float*)d_in[2];
  const float* P   = (const float*)d_in[3];
  const int*   jt  = (const int*)d_in[4];
  (void)n_in; (void)ws_size;

  const int n = in_sizes[4];
  const int H = in_sizes[2];
  const int D = in_sizes[1] / H;
  const int k = out_size / (n * (NT + 1));
  const int nslots = k * NT;
  const float tm_last = (float)((n - nslots) > 1 ? (n - nslots) : 1);
  const float l2tm = log2f(tm_last);
  const int NCmax = NT + (n + CH - 1) / CH;

  char* w = (char*)d_ws;
  size_t off = 0;
  auto take = [&](size_t bytes) -> char* {
    char* p = w + off;
    off = (off + bytes + 255) & ~(size_t)255;
    return p;
  };
  int*   meta = (int*)take(4096);
  int*   perm = (int*)take((size_t)n * 4);
  int*   tys  = (int*)take((size_t)n * 4);
  float* h    = (float*)take((size_t)n * H * 4);
  float* hsq  = (float*)take((size_t)n * 4);
  float* psq  = (float*)take((size_t)k * 4);
  float* Ms   = (float*)take((size_t)n * k * 4);
  u64*   pcol = (u64*)take((size_t)2 * NCmax * k * 8);
  u64*   plu  = (u64*)take((size_t)2 * NCmax * 8);
  float* luF  = (float*)take((size_t)n * 4);
  float* VF   = (float*)take((size_t)NT * k * 4);

  (void)hipMemsetAsync(meta, 0, 4096, stream);
  k_hist<<<(n + 255) / 256, 256, 0, stream>>>(jt, n, meta);
  k_scatter<<<(n + 255) / 256, 256, 0, stream>>>(jt, n, meta, perm, tys);
  k_hgemm<<<dim3(n / 64, H / 64), dim3(256), 0, stream>>>(emb, W1, b1, h, n, D, H);
  k_norms<<<(n + k + 3) / 4, 256, 0, stream>>>(h, P, hsq, psq, n, H, k);
  k_msort<<<dim3(n / 64, (k + 63) / 64), dim3(256), 0, stream>>>(h, P, hsq, psq, perm, Ms, n, H, k);
  k_sink<<<NCmax, 512, 0, stream>>>(Ms, meta, pcol, plu, luF, VF, k, NCmax, l2tm);
  k_epi<<<n, 256, 0, stream>>>(Ms, luF, VF, perm, tys, (float*)d_out, n, k);
}